// Round 1
// baseline (677.738 us; speedup 1.0000x reference)
//
#include <hip/hip_runtime.h>
#include <math.h>

// Problem constants (from reference): z = (64,64,64,64) fp32, codebook = 1024x64 fp32.
constexpr int DIM  = 64;
constexpr int KCB  = 1024;
constexpr int NVEC = 262144;            // 64^4 / 64
constexpr long long NELEM = 16777216LL; // 64^4

__global__ void vq_zero(float* ws) {
    if (threadIdx.x == 0) ws[0] = 0.0f;
}

__global__ __launch_bounds__(256, 4) void vq_main(
        const float* __restrict__ z,
        const float* __restrict__ cb,
        float* __restrict__ out,
        float* __restrict__ loss_acc) {
    __shared__ float esq[KCB];

    // Cooperative ||e_k||^2 precompute (4 rows/thread, negligible vs main loop).
    for (int k = threadIdx.x; k < KCB; k += 256) {
        const float* e = cb + k * DIM;
        float s0 = 0.f, s1 = 0.f, s2 = 0.f, s3 = 0.f;
        #pragma unroll
        for (int j = 0; j < DIM; j += 4) {
            float4 v = *(const float4*)(e + j);
            s0 = fmaf(v.x, v.x, s0);
            s1 = fmaf(v.y, v.y, s1);
            s2 = fmaf(v.z, v.z, s2);
            s3 = fmaf(v.w, v.w, s3);
        }
        esq[k] = (s0 + s1) + (s2 + s3);
    }
    __syncthreads();

    const int n = blockIdx.x * 256 + threadIdx.x;
    const float* x = z + (size_t)n * DIM;

    // Hold -2*x in registers (64 VGPRs). x recovered later as -0.5*m (exact).
    float m[DIM];
    #pragma unroll
    for (int j = 0; j < DIM; j += 4) {
        float4 v = *(const float4*)(x + j);
        m[j + 0] = -2.0f * v.x;
        m[j + 1] = -2.0f * v.y;
        m[j + 2] = -2.0f * v.z;
        m[j + 3] = -2.0f * v.w;
    }

    float best = INFINITY;
    int   bi   = 0;
    // k is wave-uniform -> codebook loads scalarize to s_load + SGPR-operand FMA.
    for (int k = 0; k < KCB; ++k) {
        const float* e = cb + k * DIM;
        float s0 = esq[k], s1 = 0.f, s2 = 0.f, s3 = 0.f;
        #pragma unroll
        for (int j = 0; j < DIM; j += 4) {
            s0 = fmaf(e[j + 0], m[j + 0], s0);
            s1 = fmaf(e[j + 1], m[j + 1], s1);
            s2 = fmaf(e[j + 2], m[j + 2], s2);
            s3 = fmaf(e[j + 3], m[j + 3], s3);
        }
        float s = (s0 + s1) + (s2 + s3);
        bool lt = s < best;          // strict < keeps first index on ties (matches argmin)
        best = lt ? s : best;
        bi   = lt ? k : bi;
    }

    // Epilogue: gather winning codeword, write quantized, accumulate exact ||e-x||^2.
    const float* e = cb + (size_t)bi * DIM;
    float* o = out + (size_t)n * DIM;
    float lsum = 0.f;
    #pragma unroll
    for (int j = 0; j < DIM; j += 4) {
        float4 ev = *(const float4*)(e + j);
        float x0 = -0.5f * m[j + 0];
        float x1 = -0.5f * m[j + 1];
        float x2 = -0.5f * m[j + 2];
        float x3 = -0.5f * m[j + 3];
        float d0 = ev.x - x0, d1 = ev.y - x1, d2 = ev.z - x2, d3 = ev.w - x3;
        lsum = fmaf(d0, d0, lsum);
        lsum = fmaf(d1, d1, lsum);
        lsum = fmaf(d2, d2, lsum);
        lsum = fmaf(d3, d3, lsum);
        *(float4*)(o + j) = ev;
    }

    // Wave-64 shuffle reduction, one atomic per wave.
    #pragma unroll
    for (int off = 32; off > 0; off >>= 1)
        lsum += __shfl_down(lsum, off, 64);
    if ((threadIdx.x & 63) == 0)
        atomicAdd(loss_acc, lsum);
}

__global__ void vq_finalize(const float* __restrict__ ws, float* __restrict__ out) {
    if (threadIdx.x == 0) {
        // loss = q_loss + 0.25*e_loss; both equal mean((q - z)^2) numerically.
        out[NELEM] = 1.25f * ws[0] * (1.0f / (float)NELEM);
    }
}

extern "C" void kernel_launch(void* const* d_in, const int* in_sizes, int n_in,
                              void* d_out, int out_size, void* d_ws, size_t ws_size,
                              hipStream_t stream) {
    const float* z  = (const float*)d_in[0];
    const float* cb = (const float*)d_in[1];
    float* out      = (float*)d_out;
    float* acc      = (float*)d_ws;

    vq_zero<<<1, 64, 0, stream>>>(acc);
    vq_main<<<NVEC / 256, 256, 0, stream>>>(z, cb, out, acc);
    vq_finalize<<<1, 64, 0, stream>>>(acc, out);
}

// Round 2
// 230.780 us; speedup vs baseline: 2.9367x; 2.9367x over previous
//
#include <hip/hip_runtime.h>
#include <math.h>

// z = (64,64,64,64) fp32 -> 262144 vectors of dim 64; codebook = 1024 x 64 fp32.
constexpr int DIM  = 64;
constexpr int KCB  = 1024;
constexpr int NVEC = 262144;
constexpr long long NELEM = 16777216LL;

typedef short bf16x8 __attribute__((ext_vector_type(8)));  // 8 bf16 in 4 VGPRs
typedef float f32x4  __attribute__((ext_vector_type(4)));

// fp32 -> bf16 round-to-nearest-even (bit trick; inputs are finite)
__device__ __forceinline__ short f2bf(float f) {
    union { float f; unsigned u; } v; v.f = f;
    unsigned r = (v.u + 0x7fffu + ((v.u >> 16) & 1u)) >> 16;
    return (short)r;
}

// Prep: cbbf = bf16(-2 * cb) (fold the -2 of the distance expansion into B),
// esq = ||e_k||^2 in fp32, zero the loss accumulator.
__global__ __launch_bounds__(256) void vq_prep(const float* __restrict__ cb,
        short* __restrict__ cbbf, float* __restrict__ esq, float* __restrict__ acc) {
    int i = blockIdx.x * 256 + threadIdx.x;       // 256 blocks x 256 = 65536 elems
    cbbf[i] = f2bf(-2.0f * cb[i]);
    if (blockIdx.x == 0) {
        #pragma unroll
        for (int r = 0; r < 4; ++r) {
            int row = threadIdx.x * 4 + r;        // 1024 rows / 256 threads
            const float* e = cb + row * DIM;
            float s = 0.f;
            #pragma unroll
            for (int j = 0; j < DIM; ++j) s = fmaf(e[j], e[j], s);
            esq[row] = s;
        }
        if (threadIdx.x == 0) acc[0] = 0.f;
    }
}

// Main: each wave owns 64 rows (4 MFMA A-tiles of 16x64). Loop 64 chunks of 16
// codewords: 2 MFMAs per tile (K=64 as two K=32 halves), C initialized to
// ||e||^2 so acc == full score. Running per-lane argmin, 16-lane butterfly,
// fp32 gather epilogue.
__global__ __launch_bounds__(256, 4) void vq_main(
        const float* __restrict__ z,
        const float* __restrict__ cb,
        const short* __restrict__ cbbf,
        const float* __restrict__ esq,
        float* __restrict__ out,
        float* __restrict__ loss_acc) {
    __shared__ int lds_idx[256];

    const int tid  = threadIdx.x;
    const int lane = tid & 63;
    const int wave = tid >> 6;
    const int quad = lane >> 4;
    const int lrow = lane & 15;
    const int r0   = (blockIdx.x * 4 + wave) * 64;

    // A fragments: A[m=lane&15][k=quad*8+j], two K=32 halves per tile.
    bf16x8 a0[4], a1[4];
    #pragma unroll
    for (int t = 0; t < 4; ++t) {
        const float* zr = z + (size_t)(r0 + t * 16 + lrow) * DIM + quad * 8;
        float4 p0 = *(const float4*)(zr);
        float4 p1 = *(const float4*)(zr + 4);
        float4 p2 = *(const float4*)(zr + 32);
        float4 p3 = *(const float4*)(zr + 36);
        a0[t][0] = f2bf(p0.x); a0[t][1] = f2bf(p0.y);
        a0[t][2] = f2bf(p0.z); a0[t][3] = f2bf(p0.w);
        a0[t][4] = f2bf(p1.x); a0[t][5] = f2bf(p1.y);
        a0[t][6] = f2bf(p1.z); a0[t][7] = f2bf(p1.w);
        a1[t][0] = f2bf(p2.x); a1[t][1] = f2bf(p2.y);
        a1[t][2] = f2bf(p2.z); a1[t][3] = f2bf(p2.w);
        a1[t][4] = f2bf(p3.x); a1[t][5] = f2bf(p3.y);
        a1[t][6] = f2bf(p3.z); a1[t][7] = f2bf(p3.w);
    }

    float best[4][4];
    int   bidx[4][4];
    #pragma unroll
    for (int t = 0; t < 4; ++t)
        #pragma unroll
        for (int i = 0; i < 4; ++i) { best[t][i] = INFINITY; bidx[t][i] = 0; }

    for (int c = 0; c < 64; ++c) {
        const int col = c * 16 + lrow;
        // B fragment: B[k=quad*8+j][n=lane&15]; codebook row is contiguous in k.
        const short* bp = cbbf + col * DIM + quad * 8;
        bf16x8 b0 = *(const bf16x8*)(bp);
        bf16x8 b1 = *(const bf16x8*)(bp + 32);
        const float es = esq[col];
        #pragma unroll
        for (int t = 0; t < 4; ++t) {
            f32x4 acc = { es, es, es, es };   // C layout: col=lane&15 -> all regs same col
            acc = __builtin_amdgcn_mfma_f32_16x16x32_bf16(a0[t], b0, acc, 0, 0, 0);
            acc = __builtin_amdgcn_mfma_f32_16x16x32_bf16(a1[t], b1, acc, 0, 0, 0);
            #pragma unroll
            for (int i = 0; i < 4; ++i) {
                bool lt = acc[i] < best[t][i];
                best[t][i] = lt ? acc[i] : best[t][i];
                bidx[t][i] = lt ? col    : bidx[t][i];
            }
        }
    }

    // Cross-lane argmin over the 16 cols held in each 16-lane group.
    // Row of (t,i) at this lane group = quad*4 + i; prefer lower index on ties.
    #pragma unroll
    for (int t = 0; t < 4; ++t)
        #pragma unroll
        for (int i = 0; i < 4; ++i) {
            float bs = best[t][i];
            int   bi = bidx[t][i];
            #pragma unroll
            for (int m = 1; m < 16; m <<= 1) {
                float os = __shfl_xor(bs, m, 64);
                int   oi = __shfl_xor(bi, m, 64);
                bool take = (os < bs) || ((os == bs) && (oi < bi));
                bs = take ? os : bs;
                bi = take ? oi : bi;
            }
            if (lrow == 0) lds_idx[wave * 64 + t * 16 + quad * 4 + i] = bi;
        }
    __syncthreads();

    // Epilogue: gather fp32 codebook row (output exact), fp32 loss from hot z.
    float lsum = 0.f;
    #pragma unroll 4
    for (int rr = 0; rr < 64; ++rr) {
        int idx = lds_idx[wave * 64 + rr];
        int row = r0 + rr;
        float e = cb[(size_t)idx * DIM + lane];
        float x = z[(size_t)row * DIM + lane];
        out[(size_t)row * DIM + lane] = e;
        float d = e - x;
        lsum = fmaf(d, d, lsum);
    }
    #pragma unroll
    for (int off = 32; off > 0; off >>= 1)
        lsum += __shfl_down(lsum, off, 64);
    if (lane == 0) atomicAdd(loss_acc, lsum);
}

__global__ void vq_finalize(const float* __restrict__ ws, float* __restrict__ out) {
    if (threadIdx.x == 0) {
        // q_loss + 0.25*e_loss, both equal mean((q-z)^2)
        out[NELEM] = 1.25f * ws[0] * (1.0f / (float)NELEM);
    }
}

extern "C" void kernel_launch(void* const* d_in, const int* in_sizes, int n_in,
                              void* d_out, int out_size, void* d_ws, size_t ws_size,
                              hipStream_t stream) {
    const float* z  = (const float*)d_in[0];
    const float* cb = (const float*)d_in[1];
    float* out = (float*)d_out;

    float* acc  = (float*)d_ws;
    short* cbbf = (short*)((char*)d_ws + 512);                 // 1024*64 bf16 = 128 KB
    float* esq  = (float*)((char*)d_ws + 512 + 131072);        // 1024 fp32

    vq_prep<<<256, 256, 0, stream>>>(cb, cbbf, esq, acc);
    vq_main<<<NVEC / 256, 256, 0, stream>>>(z, cb, cbbf, esq, out, acc);
    vq_finalize<<<1, 64, 0, stream>>>(acc, out);
}

// Round 3
// 223.720 us; speedup vs baseline: 3.0294x; 1.0316x over previous
//
#include <hip/hip_runtime.h>
#include <math.h>

// z = (64,64,64,64) fp32 -> 262144 vectors of dim 64; codebook = 1024 x 64 fp32.
constexpr int DIM  = 64;
constexpr int KCB  = 1024;
constexpr int NVEC = 262144;
constexpr long long NELEM = 16777216LL;

typedef short bf16x8 __attribute__((ext_vector_type(8)));  // 8 bf16 in 4 VGPRs
typedef float f32x4  __attribute__((ext_vector_type(4)));

// fp32 -> bf16 round-to-nearest-even (bit trick; inputs are finite)
__device__ __forceinline__ short f2bf(float f) {
    union { float f; unsigned u; } v; v.f = f;
    unsigned r = (v.u + 0x7fffu + ((v.u >> 16) & 1u)) >> 16;
    return (short)r;
}

// Prep: cbbf = bf16(-2*cb) (fold -2 into B), esq = ||e_k||^2, zero loss acc.
// esq rows spread across the first 1024 threads (float4 loads) — was a
// single-block scalar-load hotspot.
__global__ __launch_bounds__(256) void vq_prep(const float* __restrict__ cb,
        short* __restrict__ cbbf, float* __restrict__ esq, float* __restrict__ acc) {
    int i = blockIdx.x * 256 + threadIdx.x;       // 256 blocks x 256 = 65536 elems
    cbbf[i] = f2bf(-2.0f * cb[i]);
    if (i < KCB) {
        const float* e = cb + i * DIM;
        float s0 = 0.f, s1 = 0.f, s2 = 0.f, s3 = 0.f;
        #pragma unroll
        for (int j = 0; j < DIM; j += 4) {
            float4 v = *(const float4*)(e + j);
            s0 = fmaf(v.x, v.x, s0);
            s1 = fmaf(v.y, v.y, s1);
            s2 = fmaf(v.z, v.z, s2);
            s3 = fmaf(v.w, v.w, s3);
        }
        esq[i] = (s0 + s1) + (s2 + s3);
    }
    if (i == 0) acc[0] = 0.f;
}

// Main: wave owns 64 rows (4 A-tiles of 16x64). 64 chunks of 16 codewords:
// register double-buffered B fragments (prefetch c+1 before MFMAs of c),
// packed score|index argmin (index in low 10 mantissa bits -> and_or + min_f32,
// 2 VALU/score), fminf butterfly, fp32 gather epilogue.
__global__ __launch_bounds__(256, 4) void vq_main(
        const float* __restrict__ z,
        const float* __restrict__ cb,
        const short* __restrict__ cbbf,
        const float* __restrict__ esq,
        float* __restrict__ out,
        float* __restrict__ loss_acc) {
    __shared__ float s_esq[KCB];   // 4 KB
    __shared__ int   lds_idx[256];

    const int tid  = threadIdx.x;
    const int lane = tid & 63;
    const int wave = tid >> 6;
    const int quad = lane >> 4;
    const int lrow = lane & 15;
    const int r0   = (blockIdx.x * 4 + wave) * 64;

    for (int k = tid; k < KCB; k += 256) s_esq[k] = esq[k];

    // A fragments: A[m=lane&15][k=quad*8+j], two K=32 halves per tile.
    bf16x8 a0[4], a1[4];
    #pragma unroll
    for (int t = 0; t < 4; ++t) {
        const float* zr = z + (size_t)(r0 + t * 16 + lrow) * DIM + quad * 8;
        float4 p0 = *(const float4*)(zr);
        float4 p1 = *(const float4*)(zr + 4);
        float4 p2 = *(const float4*)(zr + 32);
        float4 p3 = *(const float4*)(zr + 36);
        a0[t][0] = f2bf(p0.x); a0[t][1] = f2bf(p0.y);
        a0[t][2] = f2bf(p0.z); a0[t][3] = f2bf(p0.w);
        a0[t][4] = f2bf(p1.x); a0[t][5] = f2bf(p1.y);
        a0[t][6] = f2bf(p1.z); a0[t][7] = f2bf(p1.w);
        a1[t][0] = f2bf(p2.x); a1[t][1] = f2bf(p2.y);
        a1[t][2] = f2bf(p2.z); a1[t][3] = f2bf(p2.w);
        a1[t][4] = f2bf(p3.x); a1[t][5] = f2bf(p3.y);
        a1[t][6] = f2bf(p3.z); a1[t][7] = f2bf(p3.w);
    }
    __syncthreads();

    float best[4][4];
    #pragma unroll
    for (int t = 0; t < 4; ++t)
        #pragma unroll
        for (int i = 0; i < 4; ++i) best[t][i] = INFINITY;

    // B fragment for chunk c: B[k=quad*8+j][n=lrow], col = c*16 + lrow.
    const short* bbase = cbbf + lrow * DIM + quad * 8;
    bf16x8 b0 = *(const bf16x8*)(bbase);
    bf16x8 b1 = *(const bf16x8*)(bbase + 32);
    float  es = s_esq[lrow];

    #pragma unroll 2
    for (int c = 0; c < 64; ++c) {
        const int cn = (c + 1) & 63;                       // wrap: redundant last prefetch
        const short* np = bbase + cn * (16 * DIM);
        bf16x8 nb0 = *(const bf16x8*)(np);
        bf16x8 nb1 = *(const bf16x8*)(np + 32);
        float  nes = s_esq[cn * 16 + lrow];

        const unsigned colv = (unsigned)(c * 16 + lrow);
        #pragma unroll
        for (int t = 0; t < 4; ++t) {
            f32x4 acc = { es, es, es, es };
            acc = __builtin_amdgcn_mfma_f32_16x16x32_bf16(a0[t], b0, acc, 0, 0, 0);
            acc = __builtin_amdgcn_mfma_f32_16x16x32_bf16(a1[t], b1, acc, 0, 0, 0);
            #pragma unroll
            for (int i = 0; i < 4; ++i) {
                unsigned u = __float_as_uint(acc[i]);
                float p = __uint_as_float((u & 0xFFFFFC00u) | colv);  // v_and_or_b32
                best[t][i] = fminf(best[t][i], p);                    // v_min_f32
            }
        }
        b0 = nb0; b1 = nb1; es = nes;
    }

    // fminf butterfly over the 16-lane col group (packed score|idx).
    #pragma unroll
    for (int t = 0; t < 4; ++t)
        #pragma unroll
        for (int i = 0; i < 4; ++i) {
            float bs = best[t][i];
            #pragma unroll
            for (int m = 1; m < 16; m <<= 1)
                bs = fminf(bs, __shfl_xor(bs, m, 64));
            if (lrow == 0)
                lds_idx[wave * 64 + t * 16 + quad * 4 + i] =
                    (int)(__float_as_uint(bs) & 0x3FFu);
        }
    __syncthreads();

    // Epilogue: gather fp32 codebook row (output exact), fp32 loss from hot z.
    float lsum = 0.f;
    #pragma unroll 4
    for (int rr = 0; rr < 64; ++rr) {
        int idx = lds_idx[wave * 64 + rr];
        int row = r0 + rr;
        float e = cb[(size_t)idx * DIM + lane];
        float x = z[(size_t)row * DIM + lane];
        out[(size_t)row * DIM + lane] = e;
        float d = e - x;
        lsum = fmaf(d, d, lsum);
    }
    #pragma unroll
    for (int off = 32; off > 0; off >>= 1)
        lsum += __shfl_down(lsum, off, 64);
    if (lane == 0) atomicAdd(loss_acc, lsum);
}

__global__ void vq_finalize(const float* __restrict__ ws, float* __restrict__ out) {
    if (threadIdx.x == 0) {
        // q_loss + 0.25*e_loss, both equal mean((q-z)^2)
        out[NELEM] = 1.25f * ws[0] * (1.0f / (float)NELEM);
    }
}

extern "C" void kernel_launch(void* const* d_in, const int* in_sizes, int n_in,
                              void* d_out, int out_size, void* d_ws, size_t ws_size,
                              hipStream_t stream) {
    const float* z  = (const float*)d_in[0];
    const float* cb = (const float*)d_in[1];
    float* out = (float*)d_out;

    float* acc  = (float*)d_ws;
    short* cbbf = (short*)((char*)d_ws + 512);                 // 1024*64 bf16 = 128 KB
    float* esq  = (float*)((char*)d_ws + 512 + 131072);        // 1024 fp32

    vq_prep<<<256, 256, 0, stream>>>(cb, cbbf, esq, acc);
    vq_main<<<NVEC / 256, 256, 0, stream>>>(z, cb, cbbf, esq, out, acc);
    vq_finalize<<<1, 64, 0, stream>>>(acc, out);
}

// Round 4
// 218.375 us; speedup vs baseline: 3.1035x; 1.0245x over previous
//
#include <hip/hip_runtime.h>
#include <math.h>

// z = (64,64,64,64) fp32 -> 262144 vectors of dim 64; codebook = 1024 x 64 fp32.
constexpr int DIM  = 64;
constexpr int KCB  = 1024;
constexpr int NVEC = 262144;
constexpr long long NELEM = 16777216LL;
constexpr int TILES = 8;                       // 128 rows per wave = 8 MFMA A-tiles
constexpr int GRID  = NVEC / (4 * TILES * 16); // 512 blocks of 256 threads

typedef short bf16x8 __attribute__((ext_vector_type(8)));  // 8 bf16 in 4 VGPRs
typedef float f32x4  __attribute__((ext_vector_type(4)));

// fp32 -> bf16 round-to-nearest-even (A-side, done once per element)
__device__ __forceinline__ short f2bf(float f) {
    union { float f; unsigned u; } v; v.f = f;
    unsigned r = (v.u + 0x7fffu + ((v.u >> 16) & 1u)) >> 16;
    return (short)r;
}

// two fp32 -> packed bf16x2 by truncation (B-side, on the fly; 2 VALU)
__device__ __forceinline__ unsigned pack_bf2(float lo, float hi) {
    return (__float_as_uint(lo) >> 16) | (__float_as_uint(hi) & 0xFFFF0000u);
}

// Single fused kernel. Each wave owns 128 rows (8 A-tiles of 16x64, bf16(-2z)).
// 64 chunks of 16 codewords: B loaded fp32 from cb (L2-hot), truncation-packed
// to bf16 in-register, C initialized to ||e||^2 (block-computed LDS table),
// packed score|index argmin. Epilogue gathers exact fp32 codebook rows, exact
// fp32 loss; last block (atomic counter) writes the final loss scalar.
__global__ __launch_bounds__(256, 2) void vq_fused(
        const float* __restrict__ z,
        const float* __restrict__ cb,
        float* __restrict__ out,
        float* __restrict__ ws) {   // ws[0]=loss sum (f32), ws[1]=block counter (u32)
    __shared__ float s_esq[KCB];    // 4 KB
    __shared__ int   lds_idx[512];  // 2 KB: 4 waves x 128 rows

    const int tid  = threadIdx.x;
    const int lane = tid & 63;
    const int wave = tid >> 6;
    const int quad = lane >> 4;
    const int lrow = lane & 15;
    const int r0   = (blockIdx.x * 4 + wave) * (TILES * 16);

    // ||e_k||^2 table, cooperatively (codebook is L2-hot across all 512 blocks).
    #pragma unroll
    for (int rr = 0; rr < 4; ++rr) {
        const int row = tid + 256 * rr;
        const float* e = cb + row * DIM;
        float s0 = 0.f, s1 = 0.f, s2 = 0.f, s3 = 0.f;
        #pragma unroll
        for (int j = 0; j < DIM; j += 4) {
            float4 v = *(const float4*)(e + j);
            s0 = fmaf(v.x, v.x, s0);
            s1 = fmaf(v.y, v.y, s1);
            s2 = fmaf(v.z, v.z, s2);
            s3 = fmaf(v.w, v.w, s3);
        }
        s_esq[row] = (s0 + s1) + (s2 + s3);
    }

    // A fragments: A[m=lane&15][k=quad*8+j], two K=32 halves, value = bf16(-2*z).
    bf16x8 a0[TILES], a1[TILES];
    #pragma unroll
    for (int t = 0; t < TILES; ++t) {
        const float* zr = z + (size_t)(r0 + t * 16 + lrow) * DIM + quad * 8;
        float4 p0 = *(const float4*)(zr);
        float4 p1 = *(const float4*)(zr + 4);
        float4 p2 = *(const float4*)(zr + 32);
        float4 p3 = *(const float4*)(zr + 36);
        a0[t][0] = f2bf(-2.f * p0.x); a0[t][1] = f2bf(-2.f * p0.y);
        a0[t][2] = f2bf(-2.f * p0.z); a0[t][3] = f2bf(-2.f * p0.w);
        a0[t][4] = f2bf(-2.f * p1.x); a0[t][5] = f2bf(-2.f * p1.y);
        a0[t][6] = f2bf(-2.f * p1.z); a0[t][7] = f2bf(-2.f * p1.w);
        a1[t][0] = f2bf(-2.f * p2.x); a1[t][1] = f2bf(-2.f * p2.y);
        a1[t][2] = f2bf(-2.f * p2.z); a1[t][3] = f2bf(-2.f * p2.w);
        a1[t][4] = f2bf(-2.f * p3.x); a1[t][5] = f2bf(-2.f * p3.y);
        a1[t][6] = f2bf(-2.f * p3.z); a1[t][7] = f2bf(-2.f * p3.w);
    }
    __syncthreads();

    float best[TILES][4];
    #pragma unroll
    for (int t = 0; t < TILES; ++t)
        #pragma unroll
        for (int i = 0; i < 4; ++i) best[t][i] = INFINITY;

    // B chunk c: col = c*16 + lrow, elements k = quad*8..+7 and +32..+39 (fp32).
    const float* bbase = cb + (size_t)lrow * DIM + quad * 8;
    float4 p0 = *(const float4*)(bbase);
    float4 p1 = *(const float4*)(bbase + 4);
    float4 p2 = *(const float4*)(bbase + 32);
    float4 p3 = *(const float4*)(bbase + 36);
    float  es = s_esq[lrow];

    #pragma unroll 1
    for (int c = 0; c < 64; ++c) {
        const int cn = (c + 1) & 63;                  // wrap: last prefetch redundant
        const float* np = bbase + cn * (16 * DIM);
        float4 q0 = *(const float4*)(np);
        float4 q1 = *(const float4*)(np + 4);
        float4 q2 = *(const float4*)(np + 32);
        float4 q3 = *(const float4*)(np + 36);
        const float nes = s_esq[cn * 16 + lrow];

        union { bf16x8 v; unsigned u[4]; } b0, b1;
        b0.u[0] = pack_bf2(p0.x, p0.y); b0.u[1] = pack_bf2(p0.z, p0.w);
        b0.u[2] = pack_bf2(p1.x, p1.y); b0.u[3] = pack_bf2(p1.z, p1.w);
        b1.u[0] = pack_bf2(p2.x, p2.y); b1.u[1] = pack_bf2(p2.z, p2.w);
        b1.u[2] = pack_bf2(p3.x, p3.y); b1.u[3] = pack_bf2(p3.z, p3.w);

        const unsigned colv = (unsigned)(c * 16 + lrow);
        #pragma unroll
        for (int t = 0; t < TILES; ++t) {
            f32x4 acc = { es, es, es, es };   // C col = lane&15 -> broadcast ||e||^2
            acc = __builtin_amdgcn_mfma_f32_16x16x32_bf16(a0[t], b0.v, acc, 0, 0, 0);
            acc = __builtin_amdgcn_mfma_f32_16x16x32_bf16(a1[t], b1.v, acc, 0, 0, 0);
            #pragma unroll
            for (int i = 0; i < 4; ++i) {
                unsigned u = __float_as_uint(acc[i]);
                float pk = __uint_as_float((u & 0xFFFFFC00u) | colv); // v_and_or_b32
                best[t][i] = fminf(best[t][i], pk);                   // v_min_f32
            }
        }
        p0 = q0; p1 = q1; p2 = q2; p3 = q3; es = nes;
    }

    // fminf butterfly over the 16-lane col group; row of (t,i) = t*16+quad*4+i.
    #pragma unroll
    for (int t = 0; t < TILES; ++t)
        #pragma unroll
        for (int i = 0; i < 4; ++i) {
            float bs = best[t][i];
            #pragma unroll
            for (int m = 1; m < 16; m <<= 1)
                bs = fminf(bs, __shfl_xor(bs, m, 64));
            if (lrow == 0)
                lds_idx[wave * 128 + t * 16 + quad * 4 + i] =
                    (int)(__float_as_uint(bs) & 0x3FFu);
        }
    __syncthreads();

    // Epilogue: gather exact fp32 codebook row, write out, exact fp32 loss.
    float lsum = 0.f;
    #pragma unroll 4
    for (int rr = 0; rr < 128; ++rr) {
        const int idx = lds_idx[wave * 128 + rr];
        const int row = r0 + rr;
        float e = cb[(size_t)idx * DIM + lane];
        float x = z[(size_t)row * DIM + lane];
        out[(size_t)row * DIM + lane] = e;
        float d = e - x;
        lsum = fmaf(d, d, lsum);
    }
    #pragma unroll
    for (int off = 32; off > 0; off >>= 1)
        lsum += __shfl_down(lsum, off, 64);
    if (lane == 0) atomicAdd(ws, lsum);            // device-scope, L2 coherence point

    __syncthreads();                               // barrier drains vmcnt -> adds done
    if (tid == 0) {
        unsigned old = atomicAdd((unsigned*)(ws + 1), 1u);
        if (old == (unsigned)(GRID - 1)) {
            float s = atomicAdd(ws, 0.0f);         // coherent read of final sum
            out[NELEM] = 1.25f * s * (1.0f / (float)NELEM);
        }
    }
}

extern "C" void kernel_launch(void* const* d_in, const int* in_sizes, int n_in,
                              void* d_out, int out_size, void* d_ws, size_t ws_size,
                              hipStream_t stream) {
    const float* z  = (const float*)d_in[0];
    const float* cb = (const float*)d_in[1];
    float* out = (float*)d_out;
    float* ws  = (float*)d_ws;

    hipMemsetAsync(ws, 0, 8, stream);              // zero loss sum + block counter
    vq_fused<<<GRID, 256, 0, stream>>>(z, cb, out, ws);
}

// Round 5
// 206.202 us; speedup vs baseline: 3.2868x; 1.0590x over previous
//
#include <hip/hip_runtime.h>
#include <math.h>

// z = (64,64,64,64) fp32 -> 262144 vectors of dim 64; codebook = 1024 x 64 fp32.
constexpr int DIM  = 64;
constexpr int KCB  = 1024;
constexpr int NVEC = 262144;
constexpr long long NELEM = 16777216LL;
constexpr int TILES = 4;               // 64 rows/wave, 256 rows/block
constexpr int GRID  = NVEC / 256;      // 1024 blocks
constexpr int CCH   = 128;             // codewords per staged LDS chunk
constexpr int NCH   = KCB / CCH;       // 8 outer chunks

typedef short bf16x8 __attribute__((ext_vector_type(8)));  // 8 bf16 = 4 VGPRs
typedef float f32x4  __attribute__((ext_vector_type(4)));

// fp32 -> bf16 round-to-nearest-even
__device__ __forceinline__ short f2bf(float f) {
    union { float f; unsigned u; } v; v.f = f;
    unsigned r = (v.u + 0x7fffu + ((v.u >> 16) & 1u)) >> 16;
    return (short)r;
}

// Prep: cbbf = bf16(-2*cb) row-major (col*64+k), esq = ||e_k||^2, zero ws[0..1].
__global__ __launch_bounds__(256) void vq_prep(const float* __restrict__ cb,
        short* __restrict__ cbbf, float* __restrict__ esq, float* __restrict__ ws) {
    int i = blockIdx.x * 256 + threadIdx.x;   // 256 blocks x 256 = 65536
    cbbf[i] = f2bf(-2.0f * cb[i]);
    if (i < KCB) {
        const float* e = cb + i * DIM;
        float s0 = 0.f, s1 = 0.f, s2 = 0.f, s3 = 0.f;
        #pragma unroll
        for (int j = 0; j < DIM; j += 4) {
            float4 v = *(const float4*)(e + j);
            s0 = fmaf(v.x, v.x, s0);
            s1 = fmaf(v.y, v.y, s1);
            s2 = fmaf(v.z, v.z, s2);
            s3 = fmaf(v.w, v.w, s3);
        }
        esq[i] = (s0 + s1) + (s2 + s3);
    }
    if (i == 0) { ws[0] = 0.f; ((unsigned*)ws)[1] = 0u; }
}

// Main: m97-style B staging. Block stages 128-codeword bf16 chunks into LDS
// (double-buffered, coalesced uint4, once per block); waves read fragments with
// ds_read_b128 via an XOR swizzle (16-B unit `part` of codeword `col` stored at
// position (part+col)&7) so staging stores AND fragment reads are <=2-way bank
// conflicts. Fragment read position collapses to the per-lane constant
// (quad+lrow)&7 because chunk col strides are multiples of 8.
__global__ __launch_bounds__(256, 4) void vq_main(
        const float* __restrict__ z,
        const float* __restrict__ cb,
        const short* __restrict__ cbbf,
        const float* __restrict__ esq,
        float* __restrict__ out,
        float* __restrict__ ws) {
    __shared__ unsigned sB[2][CCH * 32];   // 2 x 16 KB staged B
    __shared__ float    s_esq[KCB];        // 4 KB
    __shared__ int      lds_idx[256];      // 1 KB

    const int tid  = threadIdx.x;
    const int lane = tid & 63;
    const int wave = tid >> 6;
    const int quad = lane >> 4;
    const int lrow = lane & 15;
    const int r0   = (blockIdx.x * 4 + wave) * (TILES * 16);

    for (int k = tid; k < KCB; k += 256) s_esq[k] = esq[k];

    // A fragments: A[m=lane&15][k=quad*8+j], two K=32 halves, value = bf16(z).
    // (-2 is folded into B by prep.)
    bf16x8 a0[TILES], a1[TILES];
    #pragma unroll
    for (int t = 0; t < TILES; ++t) {
        const float* zr = z + (size_t)(r0 + t * 16 + lrow) * DIM + quad * 8;
        float4 p0 = *(const float4*)(zr);
        float4 p1 = *(const float4*)(zr + 4);
        float4 p2 = *(const float4*)(zr + 32);
        float4 p3 = *(const float4*)(zr + 36);
        a0[t][0] = f2bf(p0.x); a0[t][1] = f2bf(p0.y);
        a0[t][2] = f2bf(p0.z); a0[t][3] = f2bf(p0.w);
        a0[t][4] = f2bf(p1.x); a0[t][5] = f2bf(p1.y);
        a0[t][6] = f2bf(p1.z); a0[t][7] = f2bf(p1.w);
        a1[t][0] = f2bf(p2.x); a1[t][1] = f2bf(p2.y);
        a1[t][2] = f2bf(p2.z); a1[t][3] = f2bf(p2.w);
        a1[t][4] = f2bf(p3.x); a1[t][5] = f2bf(p3.y);
        a1[t][6] = f2bf(p3.z); a1[t][7] = f2bf(p3.w);
    }

    // Stage chunk 0. Chunk o = 1024 uint4 units; unit u: col=u>>3, part=u&7.
    const uint4* gB = (const uint4*)cbbf;
    {
        uint4 st[4];
        #pragma unroll
        for (int i = 0; i < 4; ++i) st[i] = gB[i * 256 + tid];
        #pragma unroll
        for (int i = 0; i < 4; ++i) {
            int u = i * 256 + tid, col = u >> 3, part = u & 7;
            *(uint4*)&sB[0][col * 32 + ((part + col) & 7) * 4] = st[i];
        }
    }
    __syncthreads();

    float best[TILES][4];
    #pragma unroll
    for (int t = 0; t < TILES; ++t)
        #pragma unroll
        for (int i = 0; i < 4; ++i) best[t][i] = INFINITY;

    const int pos0 = ((quad + lrow) & 7) * 4;       // b0: part=quad
    const int pos1 = ((quad + 4 + lrow) & 7) * 4;   // b1: part=quad+4

    for (int o = 0; o < NCH; ++o) {
        uint4 nx[4];
        if (o < NCH - 1) {
            #pragma unroll
            for (int i = 0; i < 4; ++i)
                nx[i] = gB[(o + 1) * 1024 + i * 256 + tid];
        }
        const unsigned* buf = sB[o & 1];
        #pragma unroll 2
        for (int s = 0; s < 8; ++s) {
            const int row = s * 16 + lrow;
            bf16x8 b0 = *(const bf16x8*)&buf[row * 32 + pos0];
            bf16x8 b1 = *(const bf16x8*)&buf[row * 32 + pos1];
            const float es = s_esq[o * CCH + row];
            const unsigned colv = (unsigned)(o * CCH + row);
            #pragma unroll
            for (int t = 0; t < TILES; ++t) {
                f32x4 acc = { es, es, es, es };  // C col = lane&15 -> ||e||^2 bcast
                acc = __builtin_amdgcn_mfma_f32_16x16x32_bf16(a0[t], b0, acc, 0, 0, 0);
                acc = __builtin_amdgcn_mfma_f32_16x16x32_bf16(a1[t], b1, acc, 0, 0, 0);
                #pragma unroll
                for (int i = 0; i < 4; ++i) {
                    unsigned u = __float_as_uint(acc[i]);
                    float pk = __uint_as_float((u & 0xFFFFFC00u) | colv);
                    best[t][i] = fminf(best[t][i], pk);
                }
            }
        }
        __syncthreads();                 // all reads of both bufs in-flight done
        if (o < NCH - 1) {
            #pragma unroll
            for (int i = 0; i < 4; ++i) {
                int u = i * 256 + tid, col = u >> 3, part = u & 7;
                *(uint4*)&sB[(o + 1) & 1][col * 32 + ((part + col) & 7) * 4] = nx[i];
            }
            __syncthreads();             // stores visible before next compute
        }
    }

    // fminf butterfly over 16-lane col group; row of (t,i) = t*16 + quad*4 + i.
    #pragma unroll
    for (int t = 0; t < TILES; ++t)
        #pragma unroll
        for (int i = 0; i < 4; ++i) {
            float bs = best[t][i];
            #pragma unroll
            for (int m = 1; m < 16; m <<= 1)
                bs = fminf(bs, __shfl_xor(bs, m, 64));
            if (lrow == 0)
                lds_idx[wave * 64 + t * 16 + quad * 4 + i] =
                    (int)(__float_as_uint(bs) & 0x3FFu);
        }
    __syncthreads();

    // Epilogue: gather exact fp32 codebook row, write out, exact fp32 loss.
    float lsum = 0.f;
    #pragma unroll 4
    for (int rr = 0; rr < 64; ++rr) {
        const int idx = lds_idx[wave * 64 + rr];
        const int row = r0 + rr;
        float e = cb[(size_t)idx * DIM + lane];
        float x = z[(size_t)row * DIM + lane];
        out[(size_t)row * DIM + lane] = e;
        float d = e - x;
        lsum = fmaf(d, d, lsum);
    }
    #pragma unroll
    for (int off = 32; off > 0; off >>= 1)
        lsum += __shfl_down(lsum, off, 64);
    if (lane == 0) atomicAdd(ws, lsum);

    __syncthreads();
    if (tid == 0) {
        unsigned old = atomicAdd((unsigned*)ws + 1, 1u);
        if (old == (unsigned)(GRID - 1)) {
            float s = atomicAdd(ws, 0.0f);   // coherent read of final sum
            out[NELEM] = 1.25f * s * (1.0f / (float)NELEM);
        }
    }
}

extern "C" void kernel_launch(void* const* d_in, const int* in_sizes, int n_in,
                              void* d_out, int out_size, void* d_ws, size_t ws_size,
                              hipStream_t stream) {
    const float* z  = (const float*)d_in[0];
    const float* cb = (const float*)d_in[1];
    float* out = (float*)d_out;

    float* ws   = (float*)d_ws;                           // [0]=loss, [1]=counter
    short* cbbf = (short*)((char*)d_ws + 512);            // 128 KB packed bf16
    float* esq  = (float*)((char*)d_ws + 512 + 131072);   // 1024 fp32

    vq_prep<<<256, 256, 0, stream>>>(cb, cbbf, esq, ws);
    vq_main<<<GRID, 256, 0, stream>>>(z, cb, cbbf, esq, out, ws);
}

// Round 6
// 190.746 us; speedup vs baseline: 3.5531x; 1.0810x over previous
//
#include <hip/hip_runtime.h>
#include <math.h>

// z = (64,64,64,64) fp32 -> 262144 vectors of dim 64; codebook = 1024 x 64 fp32.
constexpr int DIM  = 64;
constexpr int KCB  = 1024;
constexpr int NVEC = 262144;
constexpr long long NELEM = 16777216LL;
constexpr int TILES = 4;               // 64 rows/wave, 256 rows/block
constexpr int GRID  = NVEC / 256;      // 1024 blocks
constexpr int CCH   = 128;             // codewords per staged LDS chunk
constexpr int NCH   = KCB / CCH;       // 8 outer chunks

typedef short bf16x8 __attribute__((ext_vector_type(8)));  // 8 bf16 = 4 VGPRs
typedef float f32x4  __attribute__((ext_vector_type(4)));

// async global->LDS, 16 B per lane; LDS dest = wave-uniform base + lane*16
#define GLDS16(gp, lp) __builtin_amdgcn_global_load_lds(                      \
    (const __attribute__((address_space(1))) unsigned int*)(gp),              \
    (__attribute__((address_space(3))) unsigned int*)(lp), 16, 0, 0)

// fp32 -> bf16 round-to-nearest-even
__device__ __forceinline__ short f2bf(float f) {
    union { float f; unsigned u; } v; v.f = f;
    unsigned r = (v.u + 0x7fffu + ((v.u >> 16) & 1u)) >> 16;
    return (short)r;
}

// Prep: cbbf = bf16(-2*cb) row-major (col*64+k), esq = ||e_k||^2, zero ws[0..1].
__global__ __launch_bounds__(256) void vq_prep(const float* __restrict__ cb,
        short* __restrict__ cbbf, float* __restrict__ esq, float* __restrict__ ws) {
    int i = blockIdx.x * 256 + threadIdx.x;   // 256 blocks x 256 = 65536
    cbbf[i] = f2bf(-2.0f * cb[i]);
    if (i < KCB) {
        const float* e = cb + i * DIM;
        float s0 = 0.f, s1 = 0.f, s2 = 0.f, s3 = 0.f;
        #pragma unroll
        for (int j = 0; j < DIM; j += 4) {
            float4 v = *(const float4*)(e + j);
            s0 = fmaf(v.x, v.x, s0);
            s1 = fmaf(v.y, v.y, s1);
            s2 = fmaf(v.z, v.z, s2);
            s3 = fmaf(v.w, v.w, s3);
        }
        esq[i] = (s0 + s1) + (s2 + s3);
    }
    if (i == 0) { ws[0] = 0.f; ((unsigned*)ws)[1] = 0u; }
}

// Main. B staged into LDS by global_load_lds width=16 (no VGPRs held, no store
// insts — prefetch lives in the vmcnt queue). XOR swizzle: 16-B unit `part` of
// codeword `col` sits at LDS slot col*8 + ((part+col)&7); realized by permuting
// the *global source* address per lane (chunk-invariant -> precomputed once).
// Fragment reads are ds_read_b128 at <=2-way bank conflict (free, m136).
__global__ __launch_bounds__(256, 4) void vq_main(
        const float* __restrict__ z,
        const float* __restrict__ cb,
        const short* __restrict__ cbbf,
        const float* __restrict__ esq,
        float* __restrict__ out,
        float* __restrict__ ws) {
    __shared__ unsigned sB[2][CCH * 32];   // 2 x 16 KB staged B
    __shared__ float    s_esq[KCB];        // 4 KB
    __shared__ int      lds_idx[256];      // 1 KB

    const int tid  = threadIdx.x;
    const int lane = tid & 63;
    const int wave = tid >> 6;
    const int quad = lane >> 4;
    const int lrow = lane & 15;
    const int r0   = (blockIdx.x * 4 + wave) * (TILES * 16);

    for (int k = tid; k < KCB; k += 256) s_esq[k] = esq[k];

    // Staging geometry: slot s = wave*256 + j*64 + lane (j=0..3). The unit that
    // must land at slot s is g = col*8 + ((pos - col)&7), col=s>>3, pos=s&7.
    unsigned gofs[4];   // per-lane global byte offset within a chunk
    unsigned lofs[4];   // wave-uniform LDS byte offset (lane*16 added by HW)
    #pragma unroll
    for (int j = 0; j < 4; ++j) {
        int s = wave * 256 + j * 64 + lane;
        int col = s >> 3, pos = s & 7;
        int part = (pos - col) & 7;
        gofs[j] = (unsigned)((col * 8 + part) * 16);
        lofs[j] = (unsigned)((wave * 256 + j * 64) * 16);
    }

    // A fragments: A[m=lane&15][k=quad*8+j], two K=32 halves, value = bf16(z).
    bf16x8 a0[TILES], a1[TILES];
    #pragma unroll
    for (int t = 0; t < TILES; ++t) {
        const float* zr = z + (size_t)(r0 + t * 16 + lrow) * DIM + quad * 8;
        float4 p0 = *(const float4*)(zr);
        float4 p1 = *(const float4*)(zr + 4);
        float4 p2 = *(const float4*)(zr + 32);
        float4 p3 = *(const float4*)(zr + 36);
        a0[t][0] = f2bf(p0.x); a0[t][1] = f2bf(p0.y);
        a0[t][2] = f2bf(p0.z); a0[t][3] = f2bf(p0.w);
        a0[t][4] = f2bf(p1.x); a0[t][5] = f2bf(p1.y);
        a0[t][6] = f2bf(p1.z); a0[t][7] = f2bf(p1.w);
        a1[t][0] = f2bf(p2.x); a1[t][1] = f2bf(p2.y);
        a1[t][2] = f2bf(p2.z); a1[t][3] = f2bf(p2.w);
        a1[t][4] = f2bf(p3.x); a1[t][5] = f2bf(p3.y);
        a1[t][6] = f2bf(p3.z); a1[t][7] = f2bf(p3.w);
    }

    // Stage chunk 0 (async; the first __syncthreads drains vmcnt).
    const char* gB = (const char*)cbbf;
    #pragma unroll
    for (int j = 0; j < 4; ++j)
        GLDS16(gB + gofs[j], (char*)sB[0] + lofs[j]);
    __syncthreads();

    float best[TILES][4];
    #pragma unroll
    for (int t = 0; t < TILES; ++t)
        #pragma unroll
        for (int i = 0; i < 4; ++i) best[t][i] = INFINITY;

    const int pos0 = ((quad + lrow) & 7) * 4;       // b0: part=quad
    const int pos1 = ((quad + 4 + lrow) & 7) * 4;   // b1: part=quad+4

    for (int o = 0; o < NCH; ++o) {
        if (o < NCH - 1) {                           // async prefetch next chunk
            const char* src = gB + (o + 1) * (CCH * DIM * 2);
            #pragma unroll
            for (int j = 0; j < 4; ++j)
                GLDS16(src + gofs[j], (char*)sB[(o + 1) & 1] + lofs[j]);
        }
        const unsigned* buf = sB[o & 1];
        #pragma unroll 2
        for (int s = 0; s < 8; ++s) {
            const int row = s * 16 + lrow;
            bf16x8 b0 = *(const bf16x8*)&buf[row * 32 + pos0];
            bf16x8 b1 = *(const bf16x8*)&buf[row * 32 + pos1];
            const float es = s_esq[o * CCH + row];
            const unsigned colv = (unsigned)(o * CCH + row);
            #pragma unroll
            for (int t = 0; t < TILES; ++t) {
                f32x4 acc = { es, es, es, es };  // C col = lane&15 -> ||e||^2 bcast
                acc = __builtin_amdgcn_mfma_f32_16x16x32_bf16(a0[t], b0, acc, 0, 0, 0);
                acc = __builtin_amdgcn_mfma_f32_16x16x32_bf16(a1[t], b1, acc, 0, 0, 0);
                #pragma unroll
                for (int i = 0; i < 4; ++i) {
                    unsigned u = __float_as_uint(acc[i]);
                    float pk = __uint_as_float((u & 0xFFFFFC00u) | colv);
                    best[t][i] = fminf(best[t][i], pk);
                }
            }
        }
        // Drains the prefetch (vmcnt) and fences buffer reuse in one barrier.
        __syncthreads();
    }

    // fminf butterfly over 16-lane col group; row of (t,i) = t*16 + quad*4 + i.
    #pragma unroll
    for (int t = 0; t < TILES; ++t)
        #pragma unroll
        for (int i = 0; i < 4; ++i) {
            float bs = best[t][i];
            #pragma unroll
            for (int m = 1; m < 16; m <<= 1)
                bs = fminf(bs, __shfl_xor(bs, m, 64));
            if (lrow == 0)
                lds_idx[wave * 64 + t * 16 + quad * 4 + i] =
                    (int)(__float_as_uint(bs) & 0x3FFu);
        }
    __syncthreads();

    // Epilogue: gather exact fp32 codebook row, write out, exact fp32 loss.
    float lsum = 0.f;
    #pragma unroll 4
    for (int rr = 0; rr < 64; ++rr) {
        const int idx = lds_idx[wave * 64 + rr];
        const int row = r0 + rr;
        float e = cb[(size_t)idx * DIM + lane];
        float x = z[(size_t)row * DIM + lane];
        out[(size_t)row * DIM + lane] = e;
        float d = e - x;
        lsum = fmaf(d, d, lsum);
    }
    #pragma unroll
    for (int off = 32; off > 0; off >>= 1)
        lsum += __shfl_down(lsum, off, 64);
    if (lane == 0) atomicAdd(ws, lsum);

    __syncthreads();
    if (tid == 0) {
        unsigned old = atomicAdd((unsigned*)ws + 1, 1u);
        if (old == (unsigned)(GRID - 1)) {
            float s = atomicAdd(ws, 0.0f);   // coherent read of final sum
            out[NELEM] = 1.25f * s * (1.0f / (float)NELEM);
        }
    }
}

extern "C" void kernel_launch(void* const* d_in, const int* in_sizes, int n_in,
                              void* d_out, int out_size, void* d_ws, size_t ws_size,
                              hipStream_t stream) {
    const float* z  = (const float*)d_in[0];
    const float* cb = (const float*)d_in[1];
    float* out = (float*)d_out;

    float* ws   = (float*)d_ws;                           // [0]=loss, [1]=counter
    short* cbbf = (short*)((char*)d_ws + 512);            // 128 KB packed bf16(-2*cb)
    float* esq  = (float*)((char*)d_ws + 512 + 131072);   // 1024 fp32

    vq_prep<<<256, 256, 0, stream>>>(cb, cbbf, esq, ws);
    vq_main<<<GRID, 256, 0, stream>>>(z, cb, cbbf, esq, out, ws);
}